// Round 1
// baseline (737.599 us; speedup 1.0000x reference)
//
#include <hip/hip_runtime.h>
#include <stdint.h>

// ---------------------------------------------------------------------------
// HetAgg on MI355X. Sizes fixed per reference:
//   D=128, T=10, L=2, B=4096, ND=20000/FD=2048, NG=20000/FG=1024, NC=10000/FC=512
//
// Pipeline:
//   1) prep_ut: gru_U (L,3,128,384) f32 -> Ut bf16 [l][t][n][k]  (B-operand layout)
//   2) proj_kernel x3: P[M][128] = bf16(feats) @ bf16(W) + b   (MFMA 16x16x32)
//   3) gather_h0: h = Pd[ids]
//   4) per (l,t): xw_kernel (gathered GEMM -> xw bf16 [B*T][384]),
//                 scan_kernel (fused 10-step GRU, U in registers, h via LDS)
//   5) per l: attn_kernel (softmax over 4 candidates)
//
// MFMA fragment layouts (verified per cdna_hip_programming.md §3):
//   A: A[m=lane&15][k=(lane>>4)*8+j]   B: B[k=(lane>>4)*8+j][n=lane&15]
//   C/D: row=(lane>>4)*4+reg, col=lane&15
// ---------------------------------------------------------------------------

typedef short bf16x8 __attribute__((ext_vector_type(8)));
typedef float f32x4  __attribute__((ext_vector_type(4)));

__device__ __forceinline__ short f2bf(float f) {
  union { float f; unsigned u; } v; v.f = f;
  unsigned r = (v.u + 0x7fffu + ((v.u >> 16) & 1u)) >> 16;   // RNE
  return (short)r;
}
__device__ __forceinline__ float b2f(short s) {
  union { float f; unsigned u; } v; v.u = ((unsigned)(unsigned short)s) << 16;
  return v.f;
}
__device__ __forceinline__ f32x4 mfma_bf16(bf16x8 a, bf16x8 b, f32x4 c) {
  return __builtin_amdgcn_mfma_f32_16x16x32_bf16(a, b, c, 0, 0, 0);
}

// ---------------------------------------------------------------------------
// prep: transpose+convert gru_U (6 slices of [128 k][384 n]) -> Ut [384 n][128 k] bf16
__global__ __launch_bounds__(256) void prep_ut(const float* __restrict__ U,
                                               short* __restrict__ Ut) {
  int s = blockIdx.y;
  int o = blockIdx.x * 256 + threadIdx.x;      // 0..49151
  int k = o & 127, n = o >> 7;
  Ut[(size_t)s * 49152 + (size_t)n * 128 + k] =
      f2bf(U[(size_t)s * 49152 + (size_t)k * 384 + n]);
}

// ---------------------------------------------------------------------------
// Projection GEMM: C[M][128] = bf16(A[M][K]) @ bf16(W[K][128]) + bias
// block 256 = 4 waves; block tile 64x128, wave tile 32x64; BK=32
__global__ __launch_bounds__(256) void proj_kernel(
    const float* __restrict__ A, const float* __restrict__ W,
    const float* __restrict__ bias, float* __restrict__ C, int M, int K) {
  __shared__ alignas(16) short As[64][32];
  __shared__ alignas(16) short Bs[128][32];
  const int tid  = threadIdx.x;
  const int lane = tid & 63;
  const int w    = tid >> 6;
  const int wr   = (w >> 1) * 32;      // wave row offset in block tile
  const int wc   = (w & 1) * 64;       // wave col offset
  const int quad = lane >> 4;
  const int ln   = lane & 15;
  const int m0   = blockIdx.x * 64;

  const int arow = tid >> 2;           // 0..63
  const int acol = (tid & 3) * 8;      // 0,8,16,24
  const int brow = tid >> 3;           // k 0..31
  const int bcol = (tid & 7) * 16;     // n 0..112

  f32x4 acc[2][4];
#pragma unroll
  for (int i = 0; i < 2; i++)
#pragma unroll
    for (int j = 0; j < 4; j++) acc[i][j] = (f32x4){0.f, 0.f, 0.f, 0.f};

  for (int k0 = 0; k0 < K; k0 += 32) {
    // stage A (64x32) with f32->bf16 cvt
    {
      float av[8];
      const int gr = m0 + arow;
      if (gr < M) {
        const float* p = A + (size_t)gr * K + k0 + acol;
        float4 v0 = *(const float4*)(p);
        float4 v1 = *(const float4*)(p + 4);
        av[0]=v0.x; av[1]=v0.y; av[2]=v0.z; av[3]=v0.w;
        av[4]=v1.x; av[5]=v1.y; av[6]=v1.z; av[7]=v1.w;
      } else {
#pragma unroll
        for (int i = 0; i < 8; i++) av[i] = 0.f;
      }
      bf16x8 bv;
#pragma unroll
      for (int i = 0; i < 8; i++) bv[i] = f2bf(av[i]);
      *(bf16x8*)&As[arow][acol] = bv;
    }
    // stage W tile transposed: Bs[n][k]
    {
      const float* p = W + (size_t)(k0 + brow) * 128 + bcol;
#pragma unroll
      for (int i = 0; i < 16; i += 4) {
        float4 v = *(const float4*)(p + i);
        Bs[bcol + i + 0][brow] = f2bf(v.x);
        Bs[bcol + i + 1][brow] = f2bf(v.y);
        Bs[bcol + i + 2][brow] = f2bf(v.z);
        Bs[bcol + i + 3][brow] = f2bf(v.w);
      }
    }
    __syncthreads();
    bf16x8 af[2], bfr[4];
#pragma unroll
    for (int mi = 0; mi < 2; mi++)
      af[mi] = *(const bf16x8*)&As[wr + mi * 16 + ln][quad * 8];
#pragma unroll
    for (int nj = 0; nj < 4; nj++)
      bfr[nj] = *(const bf16x8*)&Bs[wc + nj * 16 + ln][quad * 8];
#pragma unroll
    for (int mi = 0; mi < 2; mi++)
#pragma unroll
      for (int nj = 0; nj < 4; nj++)
        acc[mi][nj] = mfma_bf16(af[mi], bfr[nj], acc[mi][nj]);
    __syncthreads();
  }

#pragma unroll
  for (int mi = 0; mi < 2; mi++)
#pragma unroll
    for (int nj = 0; nj < 4; nj++) {
      const int col = wc + nj * 16 + ln;
      const float bv = bias[col];
#pragma unroll
      for (int r = 0; r < 4; r++) {
        const int row = m0 + wr + mi * 16 + quad * 4 + r;
        if (row < M) C[(size_t)row * 128 + col] = acc[mi][nj][r] + bv;
      }
    }
}

// ---------------------------------------------------------------------------
// h0 gather: h[b][d] = Pd[ids[b]][d]
__global__ __launch_bounds__(256) void gather_h0(const float* __restrict__ Pd,
                                                 const int* __restrict__ ids,
                                                 float* __restrict__ h) {
  int i = blockIdx.x * 256 + threadIdx.x;   // < 4096*128
  int b = i >> 7, d = i & 127;
  h[i] = Pd[(size_t)ids[b] * 128 + d];
}

// ---------------------------------------------------------------------------
// xw GEMM with neighbor gather: xw[rt][384] = bf16( P[nbr[rt]] @ Wg + bg )
// M=40960, K=128; grid (640, 3), block tile 64x128 of N=384
__global__ __launch_bounds__(256) void xw_kernel(
    const float* __restrict__ P, const int* __restrict__ nbr,
    const float* __restrict__ Wg, const float* __restrict__ bg,
    short* __restrict__ xw) {
  __shared__ alignas(16) short As[64][32];
  __shared__ alignas(16) short Bs[128][32];
  const int tid  = threadIdx.x;
  const int lane = tid & 63;
  const int w    = tid >> 6;
  const int wr   = (w >> 1) * 32;
  const int wc   = (w & 1) * 64;
  const int quad = lane >> 4;
  const int ln   = lane & 15;
  const int m0    = blockIdx.x * 64;
  const int nbase = blockIdx.y * 128;

  const int arow = tid >> 2;
  const int acol = (tid & 3) * 8;
  const int brow = tid >> 3;
  const int bcol = (tid & 7) * 16;

  const int aidx = nbr[m0 + arow];       // PAD -> x row = 0 (bias-only later)

  f32x4 acc[2][4];
#pragma unroll
  for (int i = 0; i < 2; i++)
#pragma unroll
    for (int j = 0; j < 4; j++) acc[i][j] = (f32x4){0.f, 0.f, 0.f, 0.f};

  for (int k0 = 0; k0 < 128; k0 += 32) {
    {
      float av[8];
      if (aidx >= 0) {
        const float* p = P + (size_t)aidx * 128 + k0 + acol;
        float4 v0 = *(const float4*)(p);
        float4 v1 = *(const float4*)(p + 4);
        av[0]=v0.x; av[1]=v0.y; av[2]=v0.z; av[3]=v0.w;
        av[4]=v1.x; av[5]=v1.y; av[6]=v1.z; av[7]=v1.w;
      } else {
#pragma unroll
        for (int i = 0; i < 8; i++) av[i] = 0.f;
      }
      bf16x8 bv;
#pragma unroll
      for (int i = 0; i < 8; i++) bv[i] = f2bf(av[i]);
      *(bf16x8*)&As[arow][acol] = bv;
    }
    {
      const float* p = Wg + (size_t)(k0 + brow) * 384 + nbase + bcol;
#pragma unroll
      for (int i = 0; i < 16; i += 4) {
        float4 v = *(const float4*)(p + i);
        Bs[bcol + i + 0][brow] = f2bf(v.x);
        Bs[bcol + i + 1][brow] = f2bf(v.y);
        Bs[bcol + i + 2][brow] = f2bf(v.z);
        Bs[bcol + i + 3][brow] = f2bf(v.w);
      }
    }
    __syncthreads();
    bf16x8 af[2], bfr[4];
#pragma unroll
    for (int mi = 0; mi < 2; mi++)
      af[mi] = *(const bf16x8*)&As[wr + mi * 16 + ln][quad * 8];
#pragma unroll
    for (int nj = 0; nj < 4; nj++)
      bfr[nj] = *(const bf16x8*)&Bs[wc + nj * 16 + ln][quad * 8];
#pragma unroll
    for (int mi = 0; mi < 2; mi++)
#pragma unroll
      for (int nj = 0; nj < 4; nj++)
        acc[mi][nj] = mfma_bf16(af[mi], bfr[nj], acc[mi][nj]);
    __syncthreads();
  }

#pragma unroll
  for (int mi = 0; mi < 2; mi++)
#pragma unroll
    for (int nj = 0; nj < 4; nj++) {
      const int col = wc + nj * 16 + ln;
      const float bv = bg[nbase + col];
#pragma unroll
      for (int r = 0; r < 4; r++) {
        const int rt = m0 + wr + mi * 16 + quad * 4 + r;
        xw[(size_t)rt * 384 + nbase + col] = f2bf(acc[mi][nj][r] + bv);
      }
    }
}

// ---------------------------------------------------------------------------
// Fused GRU scan over T=10. Block = 16 batch rows, 4 waves; wave owns 32 cols
// of each gate (z,r,n). U kept in registers as 24 B-fragments. h round-trips
// through LDS in bf16 (C-layout -> A-layout); h/out accumulators stay f32.
__global__ __launch_bounds__(256) void scan_kernel(
    const short* __restrict__ xw, const short* __restrict__ Ut,
    const int* __restrict__ nbr, float* __restrict__ outp) {
  __shared__ alignas(16) short hs[16][128];
  __shared__ float mask_s[16][10];
  __shared__ float cinv[16];

  const int tid  = threadIdx.x;
  const int lane = tid & 63;
  const int w    = tid >> 6;
  const int nb   = w * 32;            // col base within each gate
  const int quad = lane >> 4;
  const int ln   = lane & 15;
  const int r0   = blockIdx.x * 16;   // batch row base

  if (tid < 160) {
    int i = tid / 10, t = tid % 10;
    mask_s[i][t] = (nbr[(r0 + i) * 10 + t] >= 0) ? 1.f : 0.f;
  }
  {
    short* hf = &hs[0][0];
    for (int i = tid; i < 16 * 128; i += 256) hf[i] = 0;
  }
  __syncthreads();
  if (tid < 16) {
    float s = 0.f;
    for (int t = 0; t < 10; t++) s += mask_s[tid][t];
    cinv[tid] = 1.f / fmaxf(s, 1.f);
  }

  // U fragments: u[gate][jj][ktile]; n = gate*128 + nb + jj*16 + ln
  bf16x8 u[3][2][4];
#pragma unroll
  for (int g = 0; g < 3; g++)
#pragma unroll
    for (int jj = 0; jj < 2; jj++)
#pragma unroll
      for (int kt = 0; kt < 4; kt++)
        u[g][jj][kt] = *(const bf16x8*)(Ut +
            (size_t)(g * 128 + nb + jj * 16 + ln) * 128 + kt * 32 + quad * 8);

  float hreg[2][4], oacc[2][4];
#pragma unroll
  for (int jj = 0; jj < 2; jj++)
#pragma unroll
    for (int r = 0; r < 4; r++) { hreg[jj][r] = 0.f; oacc[jj][r] = 0.f; }

  __syncthreads();

  for (int st = 0; st < 10; st++) {
    bf16x8 a[4];
#pragma unroll
    for (int kt = 0; kt < 4; kt++)
      a[kt] = *(const bf16x8*)&hs[ln][kt * 32 + quad * 8];

    f32x4 hu[3][2];
#pragma unroll
    for (int g = 0; g < 3; g++)
#pragma unroll
      for (int jj = 0; jj < 2; jj++) hu[g][jj] = (f32x4){0.f, 0.f, 0.f, 0.f};
#pragma unroll
    for (int kt = 0; kt < 4; kt++)
#pragma unroll
      for (int g = 0; g < 3; g++)
#pragma unroll
        for (int jj = 0; jj < 2; jj++)
          hu[g][jj] = mfma_bf16(a[kt], u[g][jj][kt], hu[g][jj]);

#pragma unroll
    for (int jj = 0; jj < 2; jj++) {
      const int col = nb + jj * 16 + ln;
#pragma unroll
      for (int r = 0; r < 4; r++) {
        const int row  = quad * 4 + r;
        const int grow = r0 + row;
        const short* xp = xw + (size_t)(grow * 10 + st) * 384 + col;
        const float xz = b2f(xp[0]);
        const float xr = b2f(xp[128]);
        const float xn = b2f(xp[256]);
        const float z  = 1.f / (1.f + __expf(-(xz + hu[0][jj][r])));
        const float rg = 1.f / (1.f + __expf(-(xr + hu[1][jj][r])));
        const float pn = xn + rg * hu[2][jj][r];
        const float e2 = __expf(2.f * pn);
        const float n  = (e2 - 1.f) / (e2 + 1.f);
        const float hn = (1.f - z) * n + z * hreg[jj][r];
        hreg[jj][r] = hn;
        oacc[jj][r] += hn * mask_s[row][st];
      }
    }
    __syncthreads();   // everyone done reading hs
#pragma unroll
    for (int jj = 0; jj < 2; jj++)
#pragma unroll
      for (int r = 0; r < 4; r++)
        hs[quad * 4 + r][nb + jj * 16 + ln] = f2bf(hreg[jj][r]);
    __syncthreads();   // writes visible for next step
  }

#pragma unroll
  for (int jj = 0; jj < 2; jj++)
#pragma unroll
    for (int r = 0; r < 4; r++) {
      const int row = quad * 4 + r;
      outp[(size_t)(r0 + row) * 128 + nb + jj * 16 + ln] =
          oacc[jj][r] * cinv[row];
    }
}

// ---------------------------------------------------------------------------
// Attention: one wave per batch row. e_k = att[:D].h + att[D:].C_k, leaky 0.01,
// softmax over 4, h_out = sum w_k C_k (C_0 = h).
__global__ __launch_bounds__(256) void attn_kernel(
    const float* __restrict__ hin, const float* __restrict__ cand,
    const float* __restrict__ att, float* __restrict__ hout) {
  const int tid  = threadIdx.x;
  const int lane = tid & 63;
  const int w    = tid >> 6;
  const int gb   = blockIdx.x * 4 + w;

  const float ah0 = att[lane],       ah1 = att[lane + 64];
  const float ac0 = att[128 + lane], ac1 = att[192 + lane];

  float c0[4], c1[4];
  c0[0] = hin[(size_t)gb * 128 + lane];
  c1[0] = hin[(size_t)gb * 128 + 64 + lane];
#pragma unroll
  for (int k = 1; k < 4; k++) {
    const float* p = cand + (size_t)(k - 1) * 4096 * 128 + (size_t)gb * 128;
    c0[k] = p[lane]; c1[k] = p[64 + lane];
  }

  float sh = ah0 * c0[0] + ah1 * c1[0];
#pragma unroll
  for (int m = 1; m < 64; m <<= 1) sh += __shfl_xor(sh, m);

  float e[4];
#pragma unroll
  for (int k = 0; k < 4; k++) {
    float s = ac0 * c0[k] + ac1 * c1[k];
#pragma unroll
    for (int m = 1; m < 64; m <<= 1) s += __shfl_xor(s, m);
    s += sh;
    e[k] = (s > 0.f) ? s : 0.01f * s;
  }
  const float mx = fmaxf(fmaxf(e[0], e[1]), fmaxf(e[2], e[3]));
  float wk[4], wsum = 0.f;
#pragma unroll
  for (int k = 0; k < 4; k++) { wk[k] = __expf(e[k] - mx); wsum += wk[k]; }
  const float inv = 1.f / wsum;
  float o0 = 0.f, o1 = 0.f;
#pragma unroll
  for (int k = 0; k < 4; k++) { o0 += wk[k] * c0[k]; o1 += wk[k] * c1[k]; }
  hout[(size_t)gb * 128 + lane]      = o0 * inv;
  hout[(size_t)gb * 128 + 64 + lane] = o1 * inv;
}

// ---------------------------------------------------------------------------
extern "C" void kernel_launch(void* const* d_in, const int* in_sizes, int n_in,
                              void* d_out, int out_size, void* d_ws, size_t ws_size,
                              hipStream_t stream) {
  const float* drug = (const float*)d_in[0];
  const float* gene = (const float*)d_in[1];
  const float* cell = (const float*)d_in[2];
  const float* Wd   = (const float*)d_in[3];
  const float* bd   = (const float*)d_in[4];
  const float* Wg   = (const float*)d_in[5];
  const float* bg   = (const float*)d_in[6];
  const float* Wc   = (const float*)d_in[7];
  const float* bc   = (const float*)d_in[8];
  const float* gruW = (const float*)d_in[9];
  const float* gruU = (const float*)d_in[10];
  const float* grub = (const float*)d_in[11];
  const float* att  = (const float*)d_in[12];
  const int* ids    = (const int*)d_in[13];
  const int* nbr[3] = {(const int*)d_in[14], (const int*)d_in[15],
                       (const int*)d_in[16]};

  char* ws = (char*)d_ws;
  float* Pd   = (float*)ws; ws += (size_t)20000 * 128 * 4;
  float* Pg   = (float*)ws; ws += (size_t)20000 * 128 * 4;
  float* Pc   = (float*)ws; ws += (size_t)10000 * 128 * 4;
  float* h    = (float*)ws; ws += (size_t)4096 * 128 * 4;
  float* cand = (float*)ws; ws += (size_t)3 * 4096 * 128 * 4;
  short* xwb  = (short*)ws; ws += (size_t)40960 * 384 * 2;
  short* Ut   = (short*)ws; ws += (size_t)6 * 384 * 128 * 2;

  prep_ut<<<dim3(192, 6), 256, 0, stream>>>(gruU, Ut);
  proj_kernel<<<313, 256, 0, stream>>>(drug, Wd, bd, Pd, 20000, 2048);
  proj_kernel<<<313, 256, 0, stream>>>(gene, Wg, bg, Pg, 20000, 1024);
  proj_kernel<<<157, 256, 0, stream>>>(cell, Wc, bc, Pc, 10000, 512);
  gather_h0<<<2048, 256, 0, stream>>>(Pd, ids, h);

  const float* Ptab[3] = {Pd, Pg, Pc};
  for (int l = 0; l < 2; l++) {
    for (int t = 0; t < 3; t++) {
      const int s = l * 3 + t;
      xw_kernel<<<dim3(640, 3), 256, 0, stream>>>(
          Ptab[t], nbr[t], gruW + (size_t)s * 128 * 384, grub + (size_t)s * 384,
          xwb);
      scan_kernel<<<256, 256, 0, stream>>>(
          xwb, Ut + (size_t)s * 384 * 128, nbr[t],
          cand + (size_t)t * 4096 * 128);
    }
    float* hdst = (l == 1) ? (float*)d_out : h;
    attn_kernel<<<1024, 256, 0, stream>>>(h, cand, att + l * 256, hdst);
  }
}

// Round 3
// 702.854 us; speedup vs baseline: 1.0494x; 1.0494x over previous
//
#include <hip/hip_runtime.h>
#include <stdint.h>

// ---------------------------------------------------------------------------
// HetAgg on MI355X.  D=128, T=10, L=2, B=4096; ND=20000/FD=2048,
// NG=20000/FG=1024, NC=10000/FC=512.
//
// v3 pipeline (workspace <= 60 MB; v2 overflowed and crashed the harness):
//   prep_t      : f32 [K][N] -> bf16 [N][K] (B-operand layout) for Wd/Wg/Wc,
//                 gru_W (6 slices), gru_U (6 slices)
//   proj_kernel : drug -> P f32 (for h0/attn); gene/cell -> P bf16
//   gather_h0   : h = Pd_f32[ids]
//   per (l,t)   : xw_kernel  (gathered GEMM -> xw bf16 [40960][384])
//                 scan_kernel (fused 10-step GRU, U in registers)
//   per l       : attn_kernel
//
// MFMA 16x16x32 bf16 layouts (HW-verified):
//   A: A[m=lane&15][k=quad*8+j]  B: B[k=quad*8+j][n=lane&15]
//   C/D: row=quad*4+reg, col=lane&15
// ---------------------------------------------------------------------------

typedef short bf16x8 __attribute__((ext_vector_type(8)));
typedef float f32x4  __attribute__((ext_vector_type(4)));

__device__ __forceinline__ short f2bf(float f) {
  union { float f; unsigned u; } v; v.f = f;
  unsigned r = (v.u + 0x7fffu + ((v.u >> 16) & 1u)) >> 16;   // RNE
  return (short)r;
}
__device__ __forceinline__ float b2f(short s) {
  union { float f; unsigned u; } v; v.u = ((unsigned)(unsigned short)s) << 16;
  return v.f;
}
__device__ __forceinline__ f32x4 mfma_bf16(bf16x8 a, bf16x8 b, f32x4 c) {
  return __builtin_amdgcn_mfma_f32_16x16x32_bf16(a, b, c, 0, 0, 0);
}

// ---------------------------------------------------------------------------
// transpose+cvt: src f32 [slice][K][N] -> dst bf16 [slice][N][K]
__global__ __launch_bounds__(256) void prep_t(const float* __restrict__ src,
                                              short* __restrict__ dst,
                                              int K, int N) {
  const size_t slice = (size_t)K * N;
  const float* s = src + blockIdx.y * slice;
  short* d = dst + blockIdx.y * slice;
  int i = blockIdx.x * 256 + threadIdx.x;
  if (i < K * N) {
    int k = i / N, n = i - k * N;
    d[(size_t)n * K + k] = f2bf(s[i]);
  }
}

// ---------------------------------------------------------------------------
// Projection GEMM: out[M][128] = bf16(A[M][K]) @ Wt^T + bias
// Wt is bf16 [128 n][K k]. Block 256 (4 waves), tile M=32 x N=128, BK=64.
// LDS rows padded to 72 shorts (bank stride 36 -> 2-way max, free).
// Pb (bf16) and Pf (f32) outputs are each optional.
__global__ __launch_bounds__(256) void proj_kernel(
    const float* __restrict__ A, const short* __restrict__ Wt,
    const float* __restrict__ bias, short* __restrict__ Pb,
    float* __restrict__ Pf, int M, int K) {
  __shared__ alignas(16) short As[32][72];
  __shared__ alignas(16) short Bs[128][72];
  const int tid  = threadIdx.x;
  const int lane = tid & 63;
  const int w    = tid >> 6;
  const int wc   = w * 32;            // wave col base
  const int quad = lane >> 4;
  const int ln   = lane & 15;
  const int m0   = blockIdx.x * 32;

  const int arow = tid >> 3;          // 0..31
  const int akc  = (tid & 7) * 8;     // 0..56
  const int brow = tid >> 3;          // base n, +32*j
  const int bkc  = (tid & 7) * 8;

  f32x4 acc[2][2];
#pragma unroll
  for (int i = 0; i < 2; i++)
#pragma unroll
    for (int j = 0; j < 2; j++) acc[i][j] = (f32x4){0.f, 0.f, 0.f, 0.f};

  for (int k0 = 0; k0 < K; k0 += 64) {
    // stage A (32x64) with f32->bf16 cvt; coalesced float4 pairs
    {
      const int gr = m0 + arow;
      bf16x8 bv;
      if (gr < M) {
        const float* p = A + (size_t)gr * K + k0 + akc;
        float4 v0 = *(const float4*)(p);
        float4 v1 = *(const float4*)(p + 4);
        bv[0]=f2bf(v0.x); bv[1]=f2bf(v0.y); bv[2]=f2bf(v0.z); bv[3]=f2bf(v0.w);
        bv[4]=f2bf(v1.x); bv[5]=f2bf(v1.y); bv[6]=f2bf(v1.z); bv[7]=f2bf(v1.w);
      } else {
#pragma unroll
        for (int i = 0; i < 8; i++) bv[i] = 0;
      }
      *(bf16x8*)&As[arow][akc] = bv;
    }
    // stage B (128x64) straight bf16 copy from Wt[n][k]
#pragma unroll
    for (int j = 0; j < 4; j++) {
      const int n = brow + 32 * j;
      *(bf16x8*)&Bs[n][bkc] =
          *(const bf16x8*)(Wt + (size_t)n * K + k0 + bkc);
    }
    __syncthreads();
#pragma unroll
    for (int kt = 0; kt < 2; kt++) {
      bf16x8 af[2], bfr[2];
#pragma unroll
      for (int mi = 0; mi < 2; mi++)
        af[mi] = *(const bf16x8*)&As[mi * 16 + ln][kt * 32 + quad * 8];
#pragma unroll
      for (int nj = 0; nj < 2; nj++)
        bfr[nj] = *(const bf16x8*)&Bs[wc + nj * 16 + ln][kt * 32 + quad * 8];
#pragma unroll
      for (int mi = 0; mi < 2; mi++)
#pragma unroll
        for (int nj = 0; nj < 2; nj++)
          acc[mi][nj] = mfma_bf16(af[mi], bfr[nj], acc[mi][nj]);
    }
    __syncthreads();
  }

#pragma unroll
  for (int mi = 0; mi < 2; mi++)
#pragma unroll
    for (int nj = 0; nj < 2; nj++) {
      const int col = wc + nj * 16 + ln;
      const float bv = bias[col];
#pragma unroll
      for (int r = 0; r < 4; r++) {
        const int row = m0 + mi * 16 + quad * 4 + r;
        if (row < M) {
          const float v = acc[mi][nj][r] + bv;
          if (Pb) Pb[(size_t)row * 128 + col] = f2bf(v);
          if (Pf) Pf[(size_t)row * 128 + col] = v;
        }
      }
    }
}

// ---------------------------------------------------------------------------
// h0 gather: h[b][d] = Pd_f32[ids[b]][d]
__global__ __launch_bounds__(256) void gather_h0(const float* __restrict__ Pd,
                                                 const int* __restrict__ ids,
                                                 float* __restrict__ h) {
  int i = blockIdx.x * 256 + threadIdx.x;   // < 4096*128
  int b = i >> 7, d = i & 127;
  h[i] = Pd[(size_t)ids[b] * 128 + d];
}

// ---------------------------------------------------------------------------
// xw GEMM for one (l,t): xw[rt][384] = bf16( P[nbr[rt]] @ Wts + gbs )
// grid (640, 3); block tile 64 x 128, K=128 single shot.
// Gather source: Pb (bf16) if non-null, else Pf (f32, cvt at stage — identical
// rounding to a stored bf16 table).
__global__ __launch_bounds__(256) void xw_kernel(
    const short* __restrict__ Pb, const float* __restrict__ Pf,
    const int* __restrict__ nbr, const short* __restrict__ Wts,
    const float* __restrict__ gbs, short* __restrict__ xw) {
  __shared__ alignas(16) short As[64][136];
  __shared__ alignas(16) short Bs[128][136];
  const int tid  = threadIdx.x;
  const int lane = tid & 63;
  const int w    = tid >> 6;
  const int wr   = (w >> 1) * 32;
  const int wc   = (w & 1) * 64;
  const int quad = lane >> 4;
  const int ln   = lane & 15;
  const int m0    = blockIdx.x * 64;
  const int nbase = blockIdx.y * 128;

  // stage A: gather 64 rows (128 bf16 each); 4 threads/row x 32 shorts
  {
    const int row = tid >> 2;
    const int kc  = (tid & 3) * 32;
    const int idx = nbr[m0 + row];
    if (idx >= 0) {
      if (Pb) {
        const short* p = Pb + (size_t)idx * 128 + kc;
#pragma unroll
        for (int i = 0; i < 4; i++)
          *(bf16x8*)&As[row][kc + i * 8] = *(const bf16x8*)(p + i * 8);
      } else {
        const float* p = Pf + (size_t)idx * 128 + kc;
#pragma unroll
        for (int i = 0; i < 4; i++) {
          float4 v0 = *(const float4*)(p + i * 8);
          float4 v1 = *(const float4*)(p + i * 8 + 4);
          bf16x8 bv;
          bv[0]=f2bf(v0.x); bv[1]=f2bf(v0.y); bv[2]=f2bf(v0.z); bv[3]=f2bf(v0.w);
          bv[4]=f2bf(v1.x); bv[5]=f2bf(v1.y); bv[6]=f2bf(v1.z); bv[7]=f2bf(v1.w);
          *(bf16x8*)&As[row][kc + i * 8] = bv;
        }
      }
    } else {
      bf16x8 zv;
#pragma unroll
      for (int i = 0; i < 8; i++) zv[i] = 0;
#pragma unroll
      for (int i = 0; i < 4; i++) *(bf16x8*)&As[row][kc + i * 8] = zv;
    }
  }
  // stage B: 128 rows x 128 k from Wts[nbase+n][k]; 2 threads/row x 64 shorts
  {
    const int n  = tid >> 1;
    const int kc = (tid & 1) * 64;
    const short* p = Wts + (size_t)(nbase + n) * 128 + kc;
#pragma unroll
    for (int i = 0; i < 8; i++)
      *(bf16x8*)&Bs[n][kc + i * 8] = *(const bf16x8*)(p + i * 8);
  }
  __syncthreads();

  f32x4 acc[2][4];
#pragma unroll
  for (int i = 0; i < 2; i++)
#pragma unroll
    for (int j = 0; j < 4; j++) acc[i][j] = (f32x4){0.f, 0.f, 0.f, 0.f};

#pragma unroll
  for (int kt = 0; kt < 4; kt++) {
    bf16x8 af[2], bfr[4];
#pragma unroll
    for (int mi = 0; mi < 2; mi++)
      af[mi] = *(const bf16x8*)&As[wr + mi * 16 + ln][kt * 32 + quad * 8];
#pragma unroll
    for (int nj = 0; nj < 4; nj++)
      bfr[nj] = *(const bf16x8*)&Bs[wc + nj * 16 + ln][kt * 32 + quad * 8];
#pragma unroll
    for (int mi = 0; mi < 2; mi++)
#pragma unroll
      for (int nj = 0; nj < 4; nj++)
        acc[mi][nj] = mfma_bf16(af[mi], bfr[nj], acc[mi][nj]);
  }

#pragma unroll
  for (int mi = 0; mi < 2; mi++)
#pragma unroll
    for (int nj = 0; nj < 4; nj++) {
      const int col = wc + nj * 16 + ln;
      const float bv = gbs[nbase + col];
#pragma unroll
      for (int r = 0; r < 4; r++) {
        const int rt = m0 + wr + mi * 16 + quad * 4 + r;
        xw[(size_t)rt * 384 + nbase + col] = f2bf(acc[mi][nj][r] + bv);
      }
    }
}

// ---------------------------------------------------------------------------
// Fused GRU scan over T=10 for one (l,t). Block = 16 batch rows, 4 waves;
// wave owns 32 cols of each gate. U in registers; h via LDS (bf16).
__global__ __launch_bounds__(256) void scan_kernel(
    const short* __restrict__ xw, const short* __restrict__ Utz,
    const int* __restrict__ nbr, float* __restrict__ outp) {
  __shared__ alignas(16) short hs[16][128];
  __shared__ float mask_s[16][10];
  __shared__ float cinv[16];

  const int tid  = threadIdx.x;
  const int lane = tid & 63;
  const int w    = tid >> 6;
  const int nb   = w * 32;
  const int quad = lane >> 4;
  const int ln   = lane & 15;
  const int r0   = blockIdx.x * 16;

  if (tid < 160) {
    int i = tid / 10, t = tid % 10;
    mask_s[i][t] = (nbr[(r0 + i) * 10 + t] >= 0) ? 1.f : 0.f;
  }
  {
    short* hf = &hs[0][0];
    for (int i = tid; i < 16 * 128; i += 256) hf[i] = 0;
  }
  __syncthreads();
  if (tid < 16) {
    float s = 0.f;
    for (int t = 0; t < 10; t++) s += mask_s[tid][t];
    cinv[tid] = 1.f / fmaxf(s, 1.f);
  }

  bf16x8 u[3][2][4];
#pragma unroll
  for (int g = 0; g < 3; g++)
#pragma unroll
    for (int jj = 0; jj < 2; jj++)
#pragma unroll
      for (int kt = 0; kt < 4; kt++)
        u[g][jj][kt] = *(const bf16x8*)(Utz +
            (size_t)(g * 128 + nb + jj * 16 + ln) * 128 + kt * 32 + quad * 8);

  float hreg[2][4], oacc[2][4];
#pragma unroll
  for (int jj = 0; jj < 2; jj++)
#pragma unroll
    for (int r = 0; r < 4; r++) { hreg[jj][r] = 0.f; oacc[jj][r] = 0.f; }

  __syncthreads();

  for (int st = 0; st < 10; st++) {
    bf16x8 a[4];
#pragma unroll
    for (int kt = 0; kt < 4; kt++)
      a[kt] = *(const bf16x8*)&hs[ln][kt * 32 + quad * 8];

    f32x4 hu[3][2];
#pragma unroll
    for (int g = 0; g < 3; g++)
#pragma unroll
      for (int jj = 0; jj < 2; jj++) hu[g][jj] = (f32x4){0.f, 0.f, 0.f, 0.f};
#pragma unroll
    for (int kt = 0; kt < 4; kt++)
#pragma unroll
      for (int g = 0; g < 3; g++)
#pragma unroll
        for (int jj = 0; jj < 2; jj++)
          hu[g][jj] = mfma_bf16(a[kt], u[g][jj][kt], hu[g][jj]);

#pragma unroll
    for (int jj = 0; jj < 2; jj++) {
      const int col = nb + jj * 16 + ln;
#pragma unroll
      for (int r = 0; r < 4; r++) {
        const int row  = quad * 4 + r;
        const int grow = r0 + row;
        const short* xp = xw + (size_t)(grow * 10 + st) * 384 + col;
        const float xz = b2f(xp[0]);
        const float xr = b2f(xp[128]);
        const float xn = b2f(xp[256]);
        const float zg = 1.f / (1.f + __expf(-(xz + hu[0][jj][r])));
        const float rg = 1.f / (1.f + __expf(-(xr + hu[1][jj][r])));
        const float pn = xn + rg * hu[2][jj][r];
        const float e2 = __expf(2.f * pn);
        const float n  = (e2 - 1.f) / (e2 + 1.f);
        const float hn = (1.f - zg) * n + zg * hreg[jj][r];
        hreg[jj][r] = hn;
        oacc[jj][r] += hn * mask_s[row][st];
      }
    }
    __syncthreads();
#pragma unroll
    for (int jj = 0; jj < 2; jj++)
#pragma unroll
      for (int r = 0; r < 4; r++)
        hs[quad * 4 + r][nb + jj * 16 + ln] = f2bf(hreg[jj][r]);
    __syncthreads();
  }

#pragma unroll
  for (int jj = 0; jj < 2; jj++)
#pragma unroll
    for (int r = 0; r < 4; r++) {
      const int row = quad * 4 + r;
      outp[(size_t)(r0 + row) * 128 + nb + jj * 16 + ln] =
          oacc[jj][r] * cinv[row];
    }
}

// ---------------------------------------------------------------------------
// Attention: one wave per batch row; softmax over {h, c0, c1, c2}.
__global__ __launch_bounds__(256) void attn_kernel(
    const float* __restrict__ hin, const float* __restrict__ cand,
    const float* __restrict__ att, float* __restrict__ hout) {
  const int tid  = threadIdx.x;
  const int lane = tid & 63;
  const int w    = tid >> 6;
  const int gb   = blockIdx.x * 4 + w;

  const float ah0 = att[lane],       ah1 = att[lane + 64];
  const float ac0 = att[128 + lane], ac1 = att[192 + lane];

  float c0[4], c1[4];
  c0[0] = hin[(size_t)gb * 128 + lane];
  c1[0] = hin[(size_t)gb * 128 + 64 + lane];
#pragma unroll
  for (int k = 1; k < 4; k++) {
    const float* p = cand + (size_t)(k - 1) * 4096 * 128 + (size_t)gb * 128;
    c0[k] = p[lane]; c1[k] = p[64 + lane];
  }

  float sh = ah0 * c0[0] + ah1 * c1[0];
#pragma unroll
  for (int m = 1; m < 64; m <<= 1) sh += __shfl_xor(sh, m);

  float e[4];
#pragma unroll
  for (int k = 0; k < 4; k++) {
    float s = ac0 * c0[k] + ac1 * c1[k];
#pragma unroll
    for (int m = 1; m < 64; m <<= 1) s += __shfl_xor(s, m);
    s += sh;
    e[k] = (s > 0.f) ? s : 0.01f * s;
  }
  const float mx = fmaxf(fmaxf(e[0], e[1]), fmaxf(e[2], e[3]));
  float wk[4], wsum = 0.f;
#pragma unroll
  for (int k = 0; k < 4; k++) { wk[k] = __expf(e[k] - mx); wsum += wk[k]; }
  const float inv = 1.f / wsum;
  float o0 = 0.f, o1 = 0.f;
#pragma unroll
  for (int k = 0; k < 4; k++) { o0 += wk[k] * c0[k]; o1 += wk[k] * c1[k]; }
  hout[(size_t)gb * 128 + lane]      = o0 * inv;
  hout[(size_t)gb * 128 + 64 + lane] = o1 * inv;
}

// ---------------------------------------------------------------------------
extern "C" void kernel_launch(void* const* d_in, const int* in_sizes, int n_in,
                              void* d_out, int out_size, void* d_ws, size_t ws_size,
                              hipStream_t stream) {
  const float* drug = (const float*)d_in[0];
  const float* gene = (const float*)d_in[1];
  const float* cell = (const float*)d_in[2];
  const float* Wd   = (const float*)d_in[3];
  const float* bd   = (const float*)d_in[4];
  const float* Wg   = (const float*)d_in[5];
  const float* bg   = (const float*)d_in[6];
  const float* Wc   = (const float*)d_in[7];
  const float* bc   = (const float*)d_in[8];
  const float* gruW = (const float*)d_in[9];
  const float* gruU = (const float*)d_in[10];
  const float* grub = (const float*)d_in[11];
  const float* att  = (const float*)d_in[12];
  const int* ids    = (const int*)d_in[13];
  const int* nbr[3] = {(const int*)d_in[14], (const int*)d_in[15],
                       (const int*)d_in[16]};

  char* ws = (char*)d_ws;
  auto alloc = [&](size_t bytes) {
    void* p = ws; ws += (bytes + 255) & ~(size_t)255; return p;
  };
  // total ~59.9 MB (v2's 98 MB overflowed the workspace and crashed)
  float* Pdf  = (float*)alloc((size_t)20000 * 128 * 4);   // drug proj, f32
  short* Pgb  = (short*)alloc((size_t)20000 * 128 * 2);   // gene proj, bf16
  short* Pcb  = (short*)alloc((size_t)10000 * 128 * 2);   // cell proj, bf16
  float* h    = (float*)alloc((size_t)4096 * 128 * 4);
  float* cand = (float*)alloc((size_t)3 * 4096 * 128 * 4);
  short* xwb  = (short*)alloc((size_t)40960 * 384 * 2);
  short* Wdt  = (short*)alloc((size_t)2048 * 128 * 2);
  short* Wgt  = (short*)alloc((size_t)1024 * 128 * 2);
  short* Wct  = (short*)alloc((size_t)512 * 128 * 2);
  short* gWt  = (short*)alloc((size_t)6 * 384 * 128 * 2);
  short* Ut   = (short*)alloc((size_t)6 * 384 * 128 * 2);

  // weight prep (bf16, B-operand [N][K] layout)
  prep_t<<<dim3(1024, 1), 256, 0, stream>>>(Wd, Wdt, 2048, 128);
  prep_t<<<dim3(512, 1),  256, 0, stream>>>(Wg, Wgt, 1024, 128);
  prep_t<<<dim3(256, 1),  256, 0, stream>>>(Wc, Wct, 512, 128);
  prep_t<<<dim3(192, 6),  256, 0, stream>>>(gruW, gWt, 128, 384);
  prep_t<<<dim3(192, 6),  256, 0, stream>>>(gruU, Ut,  128, 384);

  // projections (drug f32 for h0/attn; gene/cell bf16)
  proj_kernel<<<625, 256, 0, stream>>>(drug, Wdt, bd, nullptr, Pdf, 20000, 2048);
  proj_kernel<<<625, 256, 0, stream>>>(gene, Wgt, bg, Pgb, nullptr, 20000, 1024);
  proj_kernel<<<313, 256, 0, stream>>>(cell, Wct, bc, Pcb, nullptr, 10000, 512);
  gather_h0<<<2048, 256, 0, stream>>>(Pdf, ids, h);

  const short* Ptab_b[3] = {nullptr, Pgb, Pcb};
  const float* Ptab_f[3] = {Pdf, nullptr, nullptr};
  for (int l = 0; l < 2; l++) {
    for (int t = 0; t < 3; t++) {
      const int s = l * 3 + t;
      xw_kernel<<<dim3(640, 3), 256, 0, stream>>>(
          Ptab_b[t], Ptab_f[t], nbr[t], gWt + (size_t)s * 49152,
          grub + (size_t)s * 384, xwb);
      scan_kernel<<<256, 256, 0, stream>>>(
          xwb, Ut + (size_t)s * 49152, nbr[t], cand + (size_t)t * 4096 * 128);
    }
    attn_kernel<<<1024, 256, 0, stream>>>(
        h, cand, att + l * 256, (l == 1) ? (float*)d_out : h);
  }
}

// Round 4
// 672.694 us; speedup vs baseline: 1.0965x; 1.0448x over previous
//
#include <hip/hip_runtime.h>
#include <stdint.h>

// ---------------------------------------------------------------------------
// HetAgg on MI355X.  D=128, T=10, L=2, B=4096; ND=20000/FD=2048,
// NG=20000/FG=1024, NC=10000/FC=512.
//
// v4: proj gets per-block K-rotation (anti channel-camping) + BK=128 +
//     register prefetch; xw writes step-major layout [st][row][384]; scan
//     stages xw through LDS with wide loads.
//
// MFMA 16x16x32 bf16 layouts (HW-verified):
//   A: A[m=lane&15][k=quad*8+j]  B: B[k=quad*8+j][n=lane&15]
//   C/D: row=quad*4+reg, col=lane&15
// ---------------------------------------------------------------------------

typedef short bf16x8 __attribute__((ext_vector_type(8)));
typedef float f32x4  __attribute__((ext_vector_type(4)));

__device__ __forceinline__ short f2bf(float f) {
  union { float f; unsigned u; } v; v.f = f;
  unsigned r = (v.u + 0x7fffu + ((v.u >> 16) & 1u)) >> 16;   // RNE
  return (short)r;
}
__device__ __forceinline__ float b2f(short s) {
  union { float f; unsigned u; } v; v.u = ((unsigned)(unsigned short)s) << 16;
  return v.f;
}
__device__ __forceinline__ f32x4 mfma_bf16(bf16x8 a, bf16x8 b, f32x4 c) {
  return __builtin_amdgcn_mfma_f32_16x16x32_bf16(a, b, c, 0, 0, 0);
}

// ---------------------------------------------------------------------------
// transpose+cvt: src f32 [slice][K][N] -> dst bf16 [slice][N][K]
__global__ __launch_bounds__(256) void prep_t(const float* __restrict__ src,
                                              short* __restrict__ dst,
                                              int K, int N) {
  const size_t slice = (size_t)K * N;
  const float* s = src + blockIdx.y * slice;
  short* d = dst + blockIdx.y * slice;
  int i = blockIdx.x * 256 + threadIdx.x;
  if (i < K * N) {
    int k = i / N, n = i - k * N;
    d[(size_t)n * K + k] = f2bf(s[i]);
  }
}

// ---------------------------------------------------------------------------
// Projection GEMM: out[M][128] = bf16(A[M][K]) @ Wt^T + bias
// Wt bf16 [128 n][K k]. Block 256 (4 waves), tile M=32 x N=128, BK=128.
// Per-block K-rotation decorrelates HBM channel usage across blocks; A-tile
// register prefetch keeps next iter's loads in flight during MFMA.
__global__ __launch_bounds__(256) void proj_kernel(
    const float* __restrict__ A, const short* __restrict__ Wt,
    const float* __restrict__ bias, short* __restrict__ Pb,
    float* __restrict__ Pf, int M, int K) {
  __shared__ alignas(16) short As[32][136];
  __shared__ alignas(16) short Bs[128][136];
  const int tid  = threadIdx.x;
  const int lane = tid & 63;
  const int w    = tid >> 6;
  const int wc   = w * 32;            // wave col base
  const int quad = lane >> 4;
  const int ln   = lane & 15;
  const int m0   = blockIdx.x * 32;

  const int arow = tid >> 3;          // 0..31 (8 threads/row)
  const int akc  = (tid & 7) * 16;    // 16 floats = 64 B contiguous/thread
  const int brow = tid >> 1;          // 0..127 (2 threads/row)
  const int bkc  = (tid & 1) * 64;    // 64 shorts = 128 B/thread

  const int kIters = K >> 7;
  const int krot   = blockIdx.x % kIters;
  const int gr     = m0 + arow;
  const bool aok   = gr < M;
  const float* arp = A + (size_t)gr * K + akc;

  float4 areg[4];
  auto loadA = [&](int k0) {
    if (aok) {
      const float4* p = (const float4*)(arp + k0);
      areg[0] = p[0]; areg[1] = p[1]; areg[2] = p[2]; areg[3] = p[3];
    } else {
      float4 z = {0.f, 0.f, 0.f, 0.f};
      areg[0] = z; areg[1] = z; areg[2] = z; areg[3] = z;
    }
  };

  f32x4 acc[2][2];
#pragma unroll
  for (int i = 0; i < 2; i++)
#pragma unroll
    for (int j = 0; j < 2; j++) acc[i][j] = (f32x4){0.f, 0.f, 0.f, 0.f};

  loadA(krot << 7);

  for (int it = 0; it < kIters; it++) {
    int ks = krot + it; if (ks >= kIters) ks -= kIters;
    const int k0 = ks << 7;
    // cvt+store A regs (loaded for this k0)
    {
      bf16x8 v0, v1;
      v0[0]=f2bf(areg[0].x); v0[1]=f2bf(areg[0].y); v0[2]=f2bf(areg[0].z); v0[3]=f2bf(areg[0].w);
      v0[4]=f2bf(areg[1].x); v0[5]=f2bf(areg[1].y); v0[6]=f2bf(areg[1].z); v0[7]=f2bf(areg[1].w);
      v1[0]=f2bf(areg[2].x); v1[1]=f2bf(areg[2].y); v1[2]=f2bf(areg[2].z); v1[3]=f2bf(areg[2].w);
      v1[4]=f2bf(areg[3].x); v1[5]=f2bf(areg[3].y); v1[6]=f2bf(areg[3].z); v1[7]=f2bf(areg[3].w);
      *(bf16x8*)&As[arow][akc]     = v0;
      *(bf16x8*)&As[arow][akc + 8] = v1;
    }
    // stage B (128 x 128 shorts) straight bf16 copy from Wt[n][k0..]
    {
      const short* bp = Wt + (size_t)brow * K + k0 + bkc;
#pragma unroll
      for (int j = 0; j < 8; j++)
        *(bf16x8*)&Bs[brow][bkc + j * 8] = *(const bf16x8*)(bp + j * 8);
    }
    __syncthreads();
    // prefetch next A tile (in flight during MFMA)
    if (it + 1 < kIters) {
      int kn = krot + it + 1; if (kn >= kIters) kn -= kIters;
      loadA(kn << 7);
    }
#pragma unroll
    for (int kt = 0; kt < 4; kt++) {
      bf16x8 af[2], bfr[2];
#pragma unroll
      for (int mi = 0; mi < 2; mi++)
        af[mi] = *(const bf16x8*)&As[mi * 16 + ln][kt * 32 + quad * 8];
#pragma unroll
      for (int nj = 0; nj < 2; nj++)
        bfr[nj] = *(const bf16x8*)&Bs[wc + nj * 16 + ln][kt * 32 + quad * 8];
#pragma unroll
      for (int mi = 0; mi < 2; mi++)
#pragma unroll
        for (int nj = 0; nj < 2; nj++)
          acc[mi][nj] = mfma_bf16(af[mi], bfr[nj], acc[mi][nj]);
    }
    __syncthreads();
  }

#pragma unroll
  for (int mi = 0; mi < 2; mi++)
#pragma unroll
    for (int nj = 0; nj < 2; nj++) {
      const int col = wc + nj * 16 + ln;
      const float bv = bias[col];
#pragma unroll
      for (int r = 0; r < 4; r++) {
        const int row = m0 + mi * 16 + quad * 4 + r;
        if (row < M) {
          const float v = acc[mi][nj][r] + bv;
          if (Pb) Pb[(size_t)row * 128 + col] = f2bf(v);
          if (Pf) Pf[(size_t)row * 128 + col] = v;
        }
      }
    }
}

// ---------------------------------------------------------------------------
// h0 gather: h[b][d] = Pd_f32[ids[b]][d]
__global__ __launch_bounds__(256) void gather_h0(const float* __restrict__ Pd,
                                                 const int* __restrict__ ids,
                                                 float* __restrict__ h) {
  int i = blockIdx.x * 256 + threadIdx.x;   // < 4096*128
  int b = i >> 7, d = i & 127;
  h[i] = Pd[(size_t)ids[b] * 128 + d];
}

// ---------------------------------------------------------------------------
// xw GEMM for one (l,t): xwT[st][row][384] = bf16( P[nbr] @ Wts + gbs )
// grid (640, 3); block tile 64 x 128 of N=384, K=128 single shot.
__global__ __launch_bounds__(256) void xw_kernel(
    const short* __restrict__ Pb, const float* __restrict__ Pf,
    const int* __restrict__ nbr, const short* __restrict__ Wts,
    const float* __restrict__ gbs, short* __restrict__ xwT) {
  __shared__ alignas(16) short As[64][136];
  __shared__ alignas(16) short Bs[128][136];
  const int tid  = threadIdx.x;
  const int lane = tid & 63;
  const int w    = tid >> 6;
  const int wr   = (w >> 1) * 32;
  const int wc   = (w & 1) * 64;
  const int quad = lane >> 4;
  const int ln   = lane & 15;
  const int m0    = blockIdx.x * 64;
  const int nbase = blockIdx.y * 128;

  // stage A: gather 64 rows (128 bf16 each); 4 threads/row x 32 shorts
  {
    const int row = tid >> 2;
    const int kc  = (tid & 3) * 32;
    const int idx = nbr[m0 + row];
    if (idx >= 0) {
      if (Pb) {
        const short* p = Pb + (size_t)idx * 128 + kc;
#pragma unroll
        for (int i = 0; i < 4; i++)
          *(bf16x8*)&As[row][kc + i * 8] = *(const bf16x8*)(p + i * 8);
      } else {
        const float* p = Pf + (size_t)idx * 128 + kc;
#pragma unroll
        for (int i = 0; i < 4; i++) {
          float4 v0 = *(const float4*)(p + i * 8);
          float4 v1 = *(const float4*)(p + i * 8 + 4);
          bf16x8 bv;
          bv[0]=f2bf(v0.x); bv[1]=f2bf(v0.y); bv[2]=f2bf(v0.z); bv[3]=f2bf(v0.w);
          bv[4]=f2bf(v1.x); bv[5]=f2bf(v1.y); bv[6]=f2bf(v1.z); bv[7]=f2bf(v1.w);
          *(bf16x8*)&As[row][kc + i * 8] = bv;
        }
      }
    } else {
      bf16x8 zv;
#pragma unroll
      for (int i = 0; i < 8; i++) zv[i] = 0;
#pragma unroll
      for (int i = 0; i < 4; i++) *(bf16x8*)&As[row][kc + i * 8] = zv;
    }
  }
  // stage B: 128 rows x 128 k from Wts[nbase+n][k]; 2 threads/row x 64 shorts
  {
    const int n  = tid >> 1;
    const int kc = (tid & 1) * 64;
    const short* p = Wts + (size_t)(nbase + n) * 128 + kc;
#pragma unroll
    for (int i = 0; i < 8; i++)
      *(bf16x8*)&Bs[n][kc + i * 8] = *(const bf16x8*)(p + i * 8);
  }
  __syncthreads();

  f32x4 acc[2][4];
#pragma unroll
  for (int i = 0; i < 2; i++)
#pragma unroll
    for (int j = 0; j < 4; j++) acc[i][j] = (f32x4){0.f, 0.f, 0.f, 0.f};

#pragma unroll
  for (int kt = 0; kt < 4; kt++) {
    bf16x8 af[2], bfr[4];
#pragma unroll
    for (int mi = 0; mi < 2; mi++)
      af[mi] = *(const bf16x8*)&As[wr + mi * 16 + ln][kt * 32 + quad * 8];
#pragma unroll
    for (int nj = 0; nj < 4; nj++)
      bfr[nj] = *(const bf16x8*)&Bs[wc + nj * 16 + ln][kt * 32 + quad * 8];
#pragma unroll
    for (int mi = 0; mi < 2; mi++)
#pragma unroll
      for (int nj = 0; nj < 4; nj++)
        acc[mi][nj] = mfma_bf16(af[mi], bfr[nj], acc[mi][nj]);
  }

#pragma unroll
  for (int mi = 0; mi < 2; mi++)
#pragma unroll
    for (int nj = 0; nj < 4; nj++) {
      const int col = wc + nj * 16 + ln;
      const float bv = gbs[nbase + col];
#pragma unroll
      for (int r = 0; r < 4; r++) {
        const int rt   = m0 + wr + mi * 16 + quad * 4 + r;  // = row*10 + st
        const int grow = rt / 10;
        const int st   = rt - grow * 10;
        xwT[((size_t)st * 4096 + grow) * 384 + nbase + col] =
            f2bf(acc[mi][nj][r] + bv);
      }
    }
}

// ---------------------------------------------------------------------------
// Fused GRU scan over T=10 for one (l,t). Block = 16 batch rows, 4 waves.
// xw staged per-step through LDS (contiguous 12 KB dwordx4 loads from the
// step-major xwT layout); U in registers; h via LDS (bf16).
__global__ __launch_bounds__(256) void scan_kernel(
    const short* __restrict__ xwT, const short* __restrict__ Utz,
    const int* __restrict__ nbr, float* __restrict__ outp) {
  __shared__ alignas(16) short hs[16][128];
  __shared__ alignas(16) short xls[16][392];
  __shared__ float mask_s[16][10];
  __shared__ float cinv[16];

  const int tid  = threadIdx.x;
  const int lane = tid & 63;
  const int w    = tid >> 6;
  const int nb   = w * 32;
  const int quad = lane >> 4;
  const int ln   = lane & 15;
  const int r0   = blockIdx.x * 16;

  if (tid < 160) {
    int i = tid / 10, t = tid % 10;
    mask_s[i][t] = (nbr[(r0 + i) * 10 + t] >= 0) ? 1.f : 0.f;
  }
  {
    short* hf = &hs[0][0];
    for (int i = tid; i < 16 * 128; i += 256) hf[i] = 0;
  }
  __syncthreads();
  if (tid < 16) {
    float s = 0.f;
    for (int t = 0; t < 10; t++) s += mask_s[tid][t];
    cinv[tid] = 1.f / fmaxf(s, 1.f);
  }

  bf16x8 u[3][2][4];
#pragma unroll
  for (int g = 0; g < 3; g++)
#pragma unroll
    for (int jj = 0; jj < 2; jj++)
#pragma unroll
      for (int kt = 0; kt < 4; kt++)
        u[g][jj][kt] = *(const bf16x8*)(Utz +
            (size_t)(g * 128 + nb + jj * 16 + ln) * 128 + kt * 32 + quad * 8);

  // xw stage addressing (16 rows x 384 shorts = 256 threads x 24 shorts)
  int srow[3], scol[3];
#pragma unroll
  for (int j = 0; j < 3; j++) {
    const int o = tid * 24 + j * 8;
    srow[j] = o / 384;
    scol[j] = o - srow[j] * 384;
  }

  float hreg[2][4], oacc[2][4];
#pragma unroll
  for (int jj = 0; jj < 2; jj++)
#pragma unroll
    for (int r = 0; r < 4; r++) { hreg[jj][r] = 0.f; oacc[jj][r] = 0.f; }

  __syncthreads();

  for (int st = 0; st < 10; st++) {
    // a-frags from hs (published by previous step's final barrier)
    bf16x8 a[4];
#pragma unroll
    for (int kt = 0; kt < 4; kt++)
      a[kt] = *(const bf16x8*)&hs[ln][kt * 32 + quad * 8];

    // issue this step's xw loads (16 rows contiguous in step-major layout)
    const short* src = xwT + ((size_t)st * 4096 + r0) * 384;
    bf16x8 xrg[3];
#pragma unroll
    for (int j = 0; j < 3; j++)
      xrg[j] = *(const bf16x8*)(src + tid * 24 + j * 8);

    // h @ U while loads are in flight
    f32x4 hu[3][2];
#pragma unroll
    for (int g = 0; g < 3; g++)
#pragma unroll
      for (int jj = 0; jj < 2; jj++) hu[g][jj] = (f32x4){0.f, 0.f, 0.f, 0.f};
#pragma unroll
    for (int kt = 0; kt < 4; kt++)
#pragma unroll
      for (int g = 0; g < 3; g++)
#pragma unroll
        for (int jj = 0; jj < 2; jj++)
          hu[g][jj] = mfma_bf16(a[kt], u[g][jj][kt], hu[g][jj]);

#pragma unroll
    for (int j = 0; j < 3; j++)
      *(bf16x8*)&xls[srow[j]][scol[j]] = xrg[j];
    __syncthreads();   // xls staged; all hs reads done

#pragma unroll
    for (int jj = 0; jj < 2; jj++) {
      const int col = nb + jj * 16 + ln;
#pragma unroll
      for (int r = 0; r < 4; r++) {
        const int row = quad * 4 + r;
        const float xz = b2f(xls[row][col]);
        const float xr = b2f(xls[row][col + 128]);
        const float xn = b2f(xls[row][col + 256]);
        const float zg = 1.f / (1.f + __expf(-(xz + hu[0][jj][r])));
        const float rg = 1.f / (1.f + __expf(-(xr + hu[1][jj][r])));
        const float pn = xn + rg * hu[2][jj][r];
        const float e2 = __expf(2.f * pn);
        const float n  = (e2 - 1.f) / (e2 + 1.f);
        const float hn = (1.f - zg) * n + zg * hreg[jj][r];
        hreg[jj][r] = hn;
        oacc[jj][r] += hn * mask_s[row][st];
        hs[row][col] = f2bf(hn);
      }
    }
    __syncthreads();   // hs published; xls free for next step
  }

#pragma unroll
  for (int jj = 0; jj < 2; jj++)
#pragma unroll
    for (int r = 0; r < 4; r++) {
      const int row = quad * 4 + r;
      outp[(size_t)(r0 + row) * 128 + nb + jj * 16 + ln] =
          oacc[jj][r] * cinv[row];
    }
}

// ---------------------------------------------------------------------------
// Attention: one wave per batch row; softmax over {h, c0, c1, c2}.
__global__ __launch_bounds__(256) void attn_kernel(
    const float* __restrict__ hin, const float* __restrict__ cand,
    const float* __restrict__ att, float* __restrict__ hout) {
  const int tid  = threadIdx.x;
  const int lane = tid & 63;
  const int w    = tid >> 6;
  const int gb   = blockIdx.x * 4 + w;

  const float ah0 = att[lane],       ah1 = att[lane + 64];
  const float ac0 = att[128 + lane], ac1 = att[192 + lane];

  float c0[4], c1[4];
  c0[0] = hin[(size_t)gb * 128 + lane];
  c1[0] = hin[(size_t)gb * 128 + 64 + lane];
#pragma unroll
  for (int k = 1; k < 4; k++) {
    const float* p = cand + (size_t)(k - 1) * 4096 * 128 + (size_t)gb * 128;
    c0[k] = p[lane]; c1[k] = p[64 + lane];
  }

  float sh = ah0 * c0[0] + ah1 * c1[0];
#pragma unroll
  for (int m = 1; m < 64; m <<= 1) sh += __shfl_xor(sh, m);

  float e[4];
#pragma unroll
  for (int k = 0; k < 4; k++) {
    float s = ac0 * c0[k] + ac1 * c1[k];
#pragma unroll
    for (int m = 1; m < 64; m <<= 1) s += __shfl_xor(s, m);
    s += sh;
    e[k] = (s > 0.f) ? s : 0.01f * s;
  }
  const float mx = fmaxf(fmaxf(e[0], e[1]), fmaxf(e[2], e[3]));
  float wk[4], wsum = 0.f;
#pragma unroll
  for (int k = 0; k < 4; k++) { wk[k] = __expf(e[k] - mx); wsum += wk[k]; }
  const float inv = 1.f / wsum;
  float o0 = 0.f, o1 = 0.f;
#pragma unroll
  for (int k = 0; k < 4; k++) { o0 += wk[k] * c0[k]; o1 += wk[k] * c1[k]; }
  hout[(size_t)gb * 128 + lane]      = o0 * inv;
  hout[(size_t)gb * 128 + 64 + lane] = o1 * inv;
}

// ---------------------------------------------------------------------------
extern "C" void kernel_launch(void* const* d_in, const int* in_sizes, int n_in,
                              void* d_out, int out_size, void* d_ws, size_t ws_size,
                              hipStream_t stream) {
  const float* drug = (const float*)d_in[0];
  const float* gene = (const float*)d_in[1];
  const float* cell = (const float*)d_in[2];
  const float* Wd   = (const float*)d_in[3];
  const float* bd   = (const float*)d_in[4];
  const float* Wg   = (const float*)d_in[5];
  const float* bg   = (const float*)d_in[6];
  const float* Wc   = (const float*)d_in[7];
  const float* bc   = (const float*)d_in[8];
  const float* gruW = (const float*)d_in[9];
  const float* gruU = (const float*)d_in[10];
  const float* grub = (const float*)d_in[11];
  const float* att  = (const float*)d_in[12];
  const int* ids    = (const int*)d_in[13];
  const int* nbr[3] = {(const int*)d_in[14], (const int*)d_in[15],
                       (const int*)d_in[16]};

  char* ws = (char*)d_ws;
  auto alloc = [&](size_t bytes) {
    void* p = ws; ws += (bytes + 255) & ~(size_t)255; return p;
  };
  // total ~59.9 MB
  float* Pdf  = (float*)alloc((size_t)20000 * 128 * 4);   // drug proj, f32
  short* Pgb  = (short*)alloc((size_t)20000 * 128 * 2);   // gene proj, bf16
  short* Pcb  = (short*)alloc((size_t)10000 * 128 * 2);   // cell proj, bf16
  float* h    = (float*)alloc((size_t)4096 * 128 * 4);
  float* cand = (float*)alloc((size_t)3 * 4096 * 128 * 4);
  short* xwb  = (short*)alloc((size_t)40960 * 384 * 2);   // step-major [10][4096][384]
  short* Wdt  = (short*)alloc((size_t)2048 * 128 * 2);
  short* Wgt  = (short*)alloc((size_t)1024 * 128 * 2);
  short* Wct  = (short*)alloc((size_t)512 * 128 * 2);
  short* gWt  = (short*)alloc((size_t)6 * 384 * 128 * 2);
  short* Ut   = (short*)alloc((size_t)6 * 384 * 128 * 2);

  // weight prep (bf16, B-operand [N][K] layout)
  prep_t<<<dim3(1024, 1), 256, 0, stream>>>(Wd, Wdt, 2048, 128);
  prep_t<<<dim3(512, 1),  256, 0, stream>>>(Wg, Wgt, 1024, 128);
  prep_t<<<dim3(256, 1),  256, 0, stream>>>(Wc, Wct, 512, 128);
  prep_t<<<dim3(192, 6),  256, 0, stream>>>(gruW, gWt, 128, 384);
  prep_t<<<dim3(192, 6),  256, 0, stream>>>(gruU, Ut,  128, 384);

  // projections (drug f32 for h0/attn; gene/cell bf16)
  proj_kernel<<<625, 256, 0, stream>>>(drug, Wdt, bd, nullptr, Pdf, 20000, 2048);
  proj_kernel<<<625, 256, 0, stream>>>(gene, Wgt, bg, Pgb, nullptr, 20000, 1024);
  proj_kernel<<<313, 256, 0, stream>>>(cell, Wct, bc, Pcb, nullptr, 10000, 512);
  gather_h0<<<2048, 256, 0, stream>>>(Pdf, ids, h);

  const short* Ptab_b[3] = {nullptr, Pgb, Pcb};
  const float* Ptab_f[3] = {Pdf, nullptr, nullptr};
  for (int l = 0; l < 2; l++) {
    for (int t = 0; t < 3; t++) {
      const int s = l * 3 + t;
      xw_kernel<<<dim3(640, 3), 256, 0, stream>>>(
          Ptab_b[t], Ptab_f[t], nbr[t], gWt + (size_t)s * 49152,
          grub + (size_t)s * 384, xwb);
      scan_kernel<<<256, 256, 0, stream>>>(
          xwb, Ut + (size_t)s * 49152, nbr[t], cand + (size_t)t * 4096 * 128);
    }
    attn_kernel<<<1024, 256, 0, stream>>>(
        h, cand, att + l * 256, (l == 1) ? (float*)d_out : h);
  }
}